// Round 8
// baseline (416.038 us; speedup 1.0000x reference)
//
#include <hip/hip_runtime.h>
#include <cmath>

#define SQ 4096
#define SK 4096
#define NH 16
#define DH 128
#define TQ 64
#define TK 64
#define TOPK 2048
#define NEG_SENTINEL (-3.0e38f)

typedef __attribute__((ext_vector_type(8))) short short8;
typedef __attribute__((ext_vector_type(4))) float f32x4;

#define QS_BYTES ((size_t)64 * 16 * 2 * 1024 * 16)   // [qtile][head][part][unit16B]

// Split f32 x into bf16 hi + bf16 lo (truncation split; residual <= 2^-8 |x|).
__device__ __forceinline__ void cvt8(const float4 x0, const float4 x1,
                                     short8& hv, short8& lv) {
    const float xs[8] = {x0.x, x0.y, x0.z, x0.w, x1.x, x1.y, x1.z, x1.w};
    #pragma unroll
    for (int j = 0; j < 8; ++j) {
        const unsigned int b = __float_as_uint(xs[j]);
        const float hf = __uint_as_float(b & 0xFFFF0000u);
        const float r = xs[j] - hf;                      // exact
        hv[j] = (short)(b >> 16);
        lv[j] = (short)(__float_as_uint(r) >> 16);
    }
}

// ---------------------------------------------------------------------------
// Kernel 0: pre-split Q into bf16 hi/lo in per-lane-loadable unit order:
// unit u = c*64 + (row64 ^ (c&7)) within [qtile][head][part]. (unchanged)
// ---------------------------------------------------------------------------
__global__ __launch_bounds__(256) void split_q_kernel(
    const float* __restrict__ qg,    // [SQ][NH][DH]
    short8* __restrict__ qs)         // [64][16][2][1024] 16B units
{
    const int gidx = blockIdx.x * 256 + threadIdx.x;   // [row][h][c]
    const int c   = gidx & 15;
    const int h   = (gidx >> 4) & 15;
    const int row = gidx >> 8;
    const size_t gb = ((size_t)row * NH + h) * DH + c * 8;
    const float4 x0 = *(const float4*)&qg[gb];
    const float4 x1 = *(const float4*)&qg[gb + 4];
    short8 hv, lv;
    cvt8(x0, x1, hv, lv);
    const int tile = row >> 6;
    const int r    = row & 63;
    const int u    = c * 64 + (r ^ (c & 7));
    const size_t base = (size_t)(tile * 16 + h) * 2048;
    qs[base + u]        = hv;
    qs[base + 1024 + u] = lv;
}

// ---------------------------------------------------------------------------
// Kernel 1: scores via 3-term bf16-split MFMA, all-register dataflow.
// Wave mapping 4x1: wave w owns q-rows [w*16, w*16+16) x all 64 k-cols, so
// its Q fragments are unique -> loaded straight from the pre-split global
// layout per head (no LDS, no barriers in the loop). K hi/lo fragments in
// registers (converted once). Head h+1 Q prefetched under head h's MFMAs.
// ---------------------------------------------------------------------------
__global__ __launch_bounds__(256, 2) void scores_kernel(
    const short8* __restrict__ qs,   // pre-split Q
    const float* __restrict__ kg,    // [SK][DH]
    const float* __restrict__ wg,    // [SQ][NH]
    float* __restrict__ scores)      // [SQ][SK]
{
    const int bk = blockIdx.x;
    const int bq = blockIdx.y;
    const int qbase = bq * TQ;
    const int kbase = bk * TK;
    const int tid = threadIdx.x;

    if (bk > bq) {
        const float4 minf = make_float4(NEG_SENTINEL, NEG_SENTINEL, NEG_SENTINEL, NEG_SENTINEL);
        #pragma unroll
        for (int it = 0; it < 4; ++it) {
            int idx = it * 256 + tid;
            int r  = idx >> 4;
            int c4 = idx & 15;
            *(float4*)&scores[(size_t)(qbase + r) * SK + kbase + (c4 << 2)] = minf;
        }
        return;
    }

    __shared__ float Wl[TQ * NH];   // 4KB: w * scale
    #pragma unroll
    for (int it = 0; it < 4; ++it) {
        const int i = tid + it * 256;
        Wl[i] = wg[(size_t)qbase * NH + i] * 0.08838834764831845f;
    }
    __syncthreads();

    const int lane = tid & 63;
    const int wid  = tid >> 6;     // 0..3 : q-row group
    const int l15  = lane & 15;
    const int l4   = lane >> 4;

    // ---- K fragments, full 64 cols per wave (once per block) ----
    short8 bh[4][4], bl[4][4];     // [ni][s] : 128 VGPR
    #pragma unroll
    for (int ni = 0; ni < 4; ++ni)
        #pragma unroll
        for (int s = 0; s < 4; ++s) {
            const int key = kbase + ni * 16 + l15;
            const int c   = s * 4 + l4;
            const float4 x0 = *(const float4*)&kg[(size_t)key * DH + c * 8];
            const float4 x1 = *(const float4*)&kg[(size_t)key * DH + c * 8 + 4];
            cvt8(x0, x1, bh[ni][s], bl[ni][s]);
        }

    // ---- per-lane Q unit offsets (pre-split layout) ----
    int uo[4];
    #pragma unroll
    for (int s = 0; s < 4; ++s) {
        const int c = s * 4 + l4;
        uo[s] = c * 64 + ((wid * 16 + l15) ^ (c & 7));
    }

    f32x4 sacc[4];
    #pragma unroll
    for (int ni = 0; ni < 4; ++ni) sacc[ni] = (f32x4){0.f, 0.f, 0.f, 0.f};

    const short8* qt = qs + (size_t)bq * 16 * 2048;   // this q-tile, head 0

    short8 ahA[4], alA[4], ahB[4], alB[4];

#define LOADQ(AH, AL, H)                                                     \
    {                                                                        \
        const short8* hb = qt + (size_t)(H) * 2048;                          \
        _Pragma("unroll") for (int s = 0; s < 4; ++s) {                      \
            AH[s] = hb[uo[s]];                                               \
            AL[s] = hb[1024 + uo[s]];                                        \
        }                                                                    \
    }

#define COMPUTE(AH, AL, H)                                                   \
    {                                                                        \
        f32x4 lac[4];                                                        \
        _Pragma("unroll") for (int ni = 0; ni < 4; ++ni)                     \
            lac[ni] = (f32x4){0.f, 0.f, 0.f, 0.f};                           \
        _Pragma("unroll") for (int s = 0; s < 4; ++s)                        \
            _Pragma("unroll") for (int ni = 0; ni < 4; ++ni) {               \
                lac[ni] = __builtin_amdgcn_mfma_f32_16x16x32_bf16(AH[s], bh[ni][s], lac[ni], 0, 0, 0); \
                lac[ni] = __builtin_amdgcn_mfma_f32_16x16x32_bf16(AH[s], bl[ni][s], lac[ni], 0, 0, 0); \
                lac[ni] = __builtin_amdgcn_mfma_f32_16x16x32_bf16(AL[s], bh[ni][s], lac[ni], 0, 0, 0); \
            }                                                                \
        float wv[4];                                                         \
        _Pragma("unroll") for (int j = 0; j < 4; ++j)                        \
            wv[j] = Wl[(wid * 16 + l4 * 4 + j) * NH + (H)];                  \
        _Pragma("unroll") for (int ni = 0; ni < 4; ++ni)                     \
            _Pragma("unroll") for (int j = 0; j < 4; ++j)                    \
                sacc[ni][j] = fmaf(wv[j], fmaxf(lac[ni][j], 0.f), sacc[ni][j]); \
    }

    LOADQ(ahA, alA, 0)
    #pragma unroll
    for (int h = 0; h < NH; h += 2) {
        LOADQ(ahB, alB, h + 1)        // prefetch h+1 under h's MFMAs
        COMPUTE(ahA, alA, h)
        if (h + 2 < NH) LOADQ(ahA, alA, h + 2)
        COMPUTE(ahB, alB, h + 1)
    }
#undef LOADQ
#undef COMPUTE

    // ---- store with causal mask (C layout: col=lane&15, row=(lane>>4)*4+j) ----
    #pragma unroll
    for (int ni = 0; ni < 4; ++ni)
        #pragma unroll
        for (int j = 0; j < 4; ++j) {
            const int q  = qbase + wid * 16 + l4 * 4 + j;
            const int kk = kbase + ni * 16 + l15;
            scores[(size_t)q * SK + kk] = (kk <= q) ? sacc[ni][j] : NEG_SENTINEL;
        }
}

// ---------------------------------------------------------------------------
// Kernel 2: per-row bitonic sort (unchanged from round 6/7).
// ---------------------------------------------------------------------------
#define REG_PASS(J)                                                        \
    {                                                                      \
        _Pragma("unroll")                                                  \
        for (int r = 0; r < 16; ++r) {                                     \
            if ((r & (J)) == 0) {                                          \
                const int i = (t << 4) | r;                                \
                const bool up = ((i & k) == 0);                            \
                const unsigned long long a = key[r], b = key[r | (J)];     \
                const unsigned long long mx = a > b ? a : b;               \
                const unsigned long long mn = a > b ? b : a;               \
                key[r]       = up ? mx : mn;                               \
                key[r | (J)] = up ? mn : mx;                               \
            }                                                              \
        }                                                                  \
    }

template<int N>
__global__ __launch_bounds__(N / 16) void topk_kernel(
    const float* __restrict__ scores,   // [SQ][SK]
    float* __restrict__ out_idx,        // [SQ][TOPK] as float values
    int row_base)
{
    __shared__ unsigned long long lds[N];

    const int qrow = row_base + blockIdx.x;
    const int t = threadIdx.x;          // N/16 threads
    const int sw = t & 15;              // LDS swizzle

    unsigned long long key[16];
    {
        const float* rowp = scores + (size_t)qrow * SK + (t << 4);
        #pragma unroll
        for (int r4 = 0; r4 < 4; ++r4) {
            const float4 v = *(const float4*)(rowp + r4 * 4);
            const float vs[4] = {v.x, v.y, v.z, v.w};
            #pragma unroll
            for (int rr = 0; rr < 4; ++rr) {
                const int r = r4 * 4 + rr;
                const int i = (t << 4) | r;
                const unsigned int b = __float_as_uint(vs[rr]);
                const unsigned int u = (b & 0x80000000u) ? ~b : (b | 0x80000000u);
                key[r] = ((unsigned long long)u << 32) | (unsigned int)(4095 - i);
            }
        }
    }

    for (int k = 2; k <= N; k <<= 1) {
        for (int j = k >> 1; j >= 1024; j >>= 1) {
            __syncthreads();
            #pragma unroll
            for (int r = 0; r < 16; ++r) lds[(t << 4) | (r ^ sw)] = key[r];
            __syncthreads();
            #pragma unroll
            for (int r = 0; r < 16; ++r) {
                const int i = (t << 4) | r;
                const unsigned long long bb = lds[(((t << 4) | (r ^ sw))) ^ j];
                const bool take_max = (((i & k) == 0) == ((i & j) == 0));
                const bool agtb = key[r] > bb;
                key[r] = (take_max == agtb) ? key[r] : bb;
            }
        }
        {
            const int j0 = (k >> 1) < 512 ? (k >> 1) : 512;
            for (int j = j0; j >= 16; j >>= 1) {
                #pragma unroll
                for (int r = 0; r < 16; ++r) {
                    const int i = (t << 4) | r;
                    const unsigned long long bb =
                        (unsigned long long)__shfl_xor((long long)key[r], j >> 4, 64);
                    const bool take_max = (((i & k) == 0) == ((i & j) == 0));
                    const bool agtb = key[r] > bb;
                    key[r] = (take_max == agtb) ? key[r] : bb;
                }
            }
        }
        if (k > 8) REG_PASS(8)
        if (k > 4) REG_PASS(4)
        if (k > 2) REG_PASS(2)
        REG_PASS(1)
    }

    if (t < 128) {
        #pragma unroll
        for (int r4 = 0; r4 < 4; ++r4) {
            float4 o;
            o.x = (float)(4095u - (unsigned int)(key[r4 * 4 + 0] & 0xFFFFFFFFu));
            o.y = (float)(4095u - (unsigned int)(key[r4 * 4 + 1] & 0xFFFFFFFFu));
            o.z = (float)(4095u - (unsigned int)(key[r4 * 4 + 2] & 0xFFFFFFFFu));
            o.w = (float)(4095u - (unsigned int)(key[r4 * 4 + 3] & 0xFFFFFFFFu));
            *(float4*)&out_idx[(size_t)qrow * TOPK + (t << 4) + r4 * 4] = o;
        }
    }
}

extern "C" void kernel_launch(void* const* d_in, const int* in_sizes, int n_in,
                              void* d_out, int out_size, void* d_ws, size_t ws_size,
                              hipStream_t stream) {
    const float* q = (const float*)d_in[0];
    const float* k = (const float*)d_in[1];
    const float* w = (const float*)d_in[2];

    float* out        = (float*)d_out;
    float* out_topk   = out;
    float* out_scores = out + (size_t)SQ * TOPK;

    // Q-split scratch: prefer d_ws; else borrow the topk-index region
    // (written only by the final topk kernels; stream-ordered safe).
    short8* qs = (ws_size >= QS_BYTES) ? (short8*)d_ws : (short8*)out_topk;

    split_q_kernel<<<SQ * NH * 16 / 256, 256, 0, stream>>>(q, qs);

    dim3 grid(SK / TK, SQ / TQ);
    scores_kernel<<<grid, 256, 0, stream>>>(qs, k, w, out_scores);

    topk_kernel<2048><<<2048, 128, 0, stream>>>(out_scores, out_topk, 0);
    topk_kernel<4096><<<2048, 256, 0, stream>>>(out_scores, out_topk, 2048);
}

// Round 9
// 415.012 us; speedup vs baseline: 1.0025x; 1.0025x over previous
//
#include <hip/hip_runtime.h>
#include <cmath>

#define SQ 4096
#define SK 4096
#define NH 16
#define DH 128
#define TOPK 2048
#define NEG_SENTINEL (-3.0e38f)

typedef __attribute__((ext_vector_type(8))) short short8;
typedef __attribute__((ext_vector_type(4))) float f32x4;

#define QS_BYTES ((size_t)64 * 16 * 2 * 1024 * 16)   // [qtile][head][part][unit]
#define KS_BYTES ((size_t)64 * 2 * 1024 * 16)        // [ktile][part][unit]

// Split f32 into bf16 hi + lo (truncation split; residual exact).
__device__ __forceinline__ void cvt8(const float4 x0, const float4 x1,
                                     short8& hv, short8& lv) {
    const float xs[8] = {x0.x, x0.y, x0.z, x0.w, x1.x, x1.y, x1.z, x1.w};
    #pragma unroll
    for (int j = 0; j < 8; ++j) {
        const unsigned int b = __float_as_uint(xs[j]);
        const float hf = __uint_as_float(b & 0xFFFF0000u);
        const float r = xs[j] - hf;
        hv[j] = (short)(b >> 16);
        lv[j] = (short)(__float_as_uint(r) >> 16);
    }
}

// ---------------------------------------------------------------------------
// Kernel 0a: pre-split Q -> [qtile][head][2][1024] units, u = c*64+(r^(c&7)).
// ---------------------------------------------------------------------------
__global__ __launch_bounds__(256) void split_q_kernel(
    const float* __restrict__ qg, short8* __restrict__ qs)
{
    const int gidx = blockIdx.x * 256 + threadIdx.x;   // [row][h][c]
    const int c   = gidx & 15;
    const int h   = (gidx >> 4) & 15;
    const int row = gidx >> 8;
    const size_t gb = ((size_t)row * NH + h) * DH + c * 8;
    const float4 x0 = *(const float4*)&qg[gb];
    const float4 x1 = *(const float4*)&qg[gb + 4];
    short8 hv, lv;
    cvt8(x0, x1, hv, lv);
    const int u = c * 64 + ((row & 63) ^ (c & 7));
    const size_t base = (size_t)((row >> 6) * 16 + h) * 2048;
    qs[base + u]        = hv;
    qs[base + 1024 + u] = lv;
}

// ---------------------------------------------------------------------------
// Kernel 0b: pre-split K -> [ktile][2][1024] units (2 MB, L2-resident).
// ---------------------------------------------------------------------------
__global__ __launch_bounds__(256) void split_k_kernel(
    const float* __restrict__ kg, short8* __restrict__ ks)
{
    const int gidx = blockIdx.x * 256 + threadIdx.x;   // [row][c]
    const int c   = gidx & 15;
    const int row = gidx >> 4;
    const size_t gb = (size_t)row * DH + c * 8;
    const float4 x0 = *(const float4*)&kg[gb];
    const float4 x1 = *(const float4*)&kg[gb + 4];
    short8 hv, lv;
    cvt8(x0, x1, hv, lv);
    const int u = c * 64 + ((row & 63) ^ (c & 7));
    const size_t base = (size_t)(row >> 6) * 2048;
    ks[base + u]        = hv;
    ks[base + 1024 + u] = lv;
}

// ---------------------------------------------------------------------------
// Kernel 1: scores. Block = q-tile(64 rows) x 2 k-tiles(128 cols).
// grid(64,32): x=bq -> linear id % 8 == bq % 8 -> same-XCD L2 reuse of qs.
// Wave = 32 q-rows (mi=2) x 64 k-cols (its own k-tile via wk). All fragments
// per-lane from pre-split global; no LDS in the hot loop, no barriers.
// 3-term bf16 split MFMA (hh+hl+lh).
// ---------------------------------------------------------------------------
__global__ __launch_bounds__(256) void scores_kernel(
    const short8* __restrict__ qs,   // pre-split Q
    const short8* __restrict__ ksp,  // pre-split K (may be null)
    const float* __restrict__ kg,    // [SK][DH] f32 fallback
    const float* __restrict__ wg,    // [SQ][NH]
    float* __restrict__ scores)      // [SQ][SK]
{
    const int bq  = blockIdx.x;
    const int kgi = blockIdx.y;
    const int qbase  = bq * 64;
    const int kbase0 = kgi * 128;
    const int tid = threadIdx.x;

    if (kbase0 > qbase + 63) {
        // fully masked 64x128 region
        const float4 minf = make_float4(NEG_SENTINEL, NEG_SENTINEL, NEG_SENTINEL, NEG_SENTINEL);
        #pragma unroll
        for (int it = 0; it < 8; ++it) {
            const int idx = it * 256 + tid;       // 0..2047 float4
            const int r  = idx >> 5;              // 32 float4 per row
            const int c4 = idx & 31;
            *(float4*)&scores[(size_t)(qbase + r) * SK + kbase0 + (c4 << 2)] = minf;
        }
        return;
    }

    __shared__ float Wl[64 * NH];   // w * scale for this q-tile
    #pragma unroll
    for (int it = 0; it < 4; ++it) {
        const int i = tid + it * 256;
        Wl[i] = wg[(size_t)qbase * NH + i] * 0.08838834764831845f;
    }
    __syncthreads();

    const int lane = tid & 63;
    const int wid  = tid >> 6;
    const int wq   = wid >> 1;          // 0,1 : q-row half
    const int wk   = wid & 1;           // 0,1 : k-tile within group
    const int l15  = lane & 15;
    const int l4   = lane >> 4;

    const int ktile = kgi * 2 + wk;
    const int kbase = ktile * 64;
    const bool kt_live = (kbase <= qbase + 63);

    // A (Q) unit offsets
    int uoff[2][4];
    #pragma unroll
    for (int mi = 0; mi < 2; ++mi)
        #pragma unroll
        for (int s = 0; s < 4; ++s) {
            const int c = s * 4 + l4;
            uoff[mi][s] = c * 64 + ((wq * 32 + mi * 16 + l15) ^ (c & 7));
        }
    // B (K) unit offsets
    int boff[4][4];
    #pragma unroll
    for (int ni = 0; ni < 4; ++ni)
        #pragma unroll
        for (int s = 0; s < 4; ++s) {
            const int c = s * 4 + l4;
            boff[ni][s] = c * 64 + ((ni * 16 + l15) ^ (c & 7));
        }

    f32x4 sacc[2][4];
    #pragma unroll
    for (int mi = 0; mi < 2; ++mi)
        #pragma unroll
        for (int ni = 0; ni < 4; ++ni) sacc[mi][ni] = (f32x4){0.f, 0.f, 0.f, 0.f};

    if (kt_live) {
        const short8* qt0 = qs + (size_t)bq * 16 * 2048;
        const short8* kb  = ksp ? ksp + (size_t)ktile * 2048 : (const short8*)0;

        #pragma unroll 4
        for (int h = 0; h < NH; ++h) {
            const short8* qh = qt0 + (size_t)h * 2048;
            short8 ah[2][4], al[2][4];
            #pragma unroll
            for (int mi = 0; mi < 2; ++mi)
                #pragma unroll
                for (int s = 0; s < 4; ++s) {
                    ah[mi][s] = qh[uoff[mi][s]];
                    al[mi][s] = qh[1024 + uoff[mi][s]];
                }

            f32x4 lac[2][4];
            #pragma unroll
            for (int mi = 0; mi < 2; ++mi)
                #pragma unroll
                for (int ni = 0; ni < 4; ++ni) lac[mi][ni] = (f32x4){0.f, 0.f, 0.f, 0.f};

            #pragma unroll
            for (int s = 0; s < 4; ++s) {
                short8 bh[4], bl[4];
                if (kb) {
                    #pragma unroll
                    for (int ni = 0; ni < 4; ++ni) {
                        bh[ni] = kb[boff[ni][s]];
                        bl[ni] = kb[1024 + boff[ni][s]];
                    }
                } else {
                    #pragma unroll
                    for (int ni = 0; ni < 4; ++ni) {
                        const int row = kbase + ni * 16 + l15;
                        const int c   = s * 4 + l4;
                        const float4 x0 = *(const float4*)&kg[(size_t)row * DH + c * 8];
                        const float4 x1 = *(const float4*)&kg[(size_t)row * DH + c * 8 + 4];
                        cvt8(x0, x1, bh[ni], bl[ni]);
                    }
                }
                #pragma unroll
                for (int mi = 0; mi < 2; ++mi)
                    #pragma unroll
                    for (int ni = 0; ni < 4; ++ni) {
                        lac[mi][ni] = __builtin_amdgcn_mfma_f32_16x16x32_bf16(ah[mi][s], bh[ni], lac[mi][ni], 0, 0, 0);
                        lac[mi][ni] = __builtin_amdgcn_mfma_f32_16x16x32_bf16(ah[mi][s], bl[ni], lac[mi][ni], 0, 0, 0);
                        lac[mi][ni] = __builtin_amdgcn_mfma_f32_16x16x32_bf16(al[mi][s], bh[ni], lac[mi][ni], 0, 0, 0);
                    }
            }

            float wv[2][4];
            #pragma unroll
            for (int mi = 0; mi < 2; ++mi)
                #pragma unroll
                for (int j = 0; j < 4; ++j)
                    wv[mi][j] = Wl[(wq * 32 + mi * 16 + l4 * 4 + j) * NH + h];
            #pragma unroll
            for (int mi = 0; mi < 2; ++mi)
                #pragma unroll
                for (int ni = 0; ni < 4; ++ni)
                    #pragma unroll
                    for (int j = 0; j < 4; ++j)
                        sacc[mi][ni][j] = fmaf(wv[mi][j], fmaxf(lac[mi][ni][j], 0.f), sacc[mi][ni][j]);
        }
    }

    #pragma unroll
    for (int mi = 0; mi < 2; ++mi)
        #pragma unroll
        for (int ni = 0; ni < 4; ++ni)
            #pragma unroll
            for (int j = 0; j < 4; ++j) {
                const int q  = qbase + wq * 32 + mi * 16 + l4 * 4 + j;
                const int kk = kbase + ni * 16 + l15;
                scores[(size_t)q * SK + kk] =
                    (kt_live && kk <= q) ? sacc[mi][ni][j] : NEG_SENTINEL;
            }
}

// ---------------------------------------------------------------------------
// Kernel 2: per-row bitonic sort (unchanged).
// ---------------------------------------------------------------------------
#define REG_PASS(J)                                                        \
    {                                                                      \
        _Pragma("unroll")                                                  \
        for (int r = 0; r < 16; ++r) {                                     \
            if ((r & (J)) == 0) {                                          \
                const int i = (t << 4) | r;                                \
                const bool up = ((i & k) == 0);                            \
                const unsigned long long a = key[r], b = key[r | (J)];     \
                const unsigned long long mx = a > b ? a : b;               \
                const unsigned long long mn = a > b ? b : a;               \
                key[r]       = up ? mx : mn;                               \
                key[r | (J)] = up ? mn : mx;                               \
            }                                                              \
        }                                                                  \
    }

template<int N>
__global__ __launch_bounds__(N / 16) void topk_kernel(
    const float* __restrict__ scores,
    float* __restrict__ out_idx,
    int row_base)
{
    __shared__ unsigned long long lds[N];

    const int qrow = row_base + blockIdx.x;
    const int t = threadIdx.x;
    const int sw = t & 15;

    unsigned long long key[16];
    {
        const float* rowp = scores + (size_t)qrow * SK + (t << 4);
        #pragma unroll
        for (int r4 = 0; r4 < 4; ++r4) {
            const float4 v = *(const float4*)(rowp + r4 * 4);
            const float vs[4] = {v.x, v.y, v.z, v.w};
            #pragma unroll
            for (int rr = 0; rr < 4; ++rr) {
                const int r = r4 * 4 + rr;
                const int i = (t << 4) | r;
                const unsigned int b = __float_as_uint(vs[rr]);
                const unsigned int u = (b & 0x80000000u) ? ~b : (b | 0x80000000u);
                key[r] = ((unsigned long long)u << 32) | (unsigned int)(4095 - i);
            }
        }
    }

    for (int k = 2; k <= N; k <<= 1) {
        for (int j = k >> 1; j >= 1024; j >>= 1) {
            __syncthreads();
            #pragma unroll
            for (int r = 0; r < 16; ++r) lds[(t << 4) | (r ^ sw)] = key[r];
            __syncthreads();
            #pragma unroll
            for (int r = 0; r < 16; ++r) {
                const int i = (t << 4) | r;
                const unsigned long long bb = lds[(((t << 4) | (r ^ sw))) ^ j];
                const bool take_max = (((i & k) == 0) == ((i & j) == 0));
                const bool agtb = key[r] > bb;
                key[r] = (take_max == agtb) ? key[r] : bb;
            }
        }
        {
            const int j0 = (k >> 1) < 512 ? (k >> 1) : 512;
            for (int j = j0; j >= 16; j >>= 1) {
                #pragma unroll
                for (int r = 0; r < 16; ++r) {
                    const int i = (t << 4) | r;
                    const unsigned long long bb =
                        (unsigned long long)__shfl_xor((long long)key[r], j >> 4, 64);
                    const bool take_max = (((i & k) == 0) == ((i & j) == 0));
                    const bool agtb = key[r] > bb;
                    key[r] = (take_max == agtb) ? key[r] : bb;
                }
            }
        }
        if (k > 8) REG_PASS(8)
        if (k > 4) REG_PASS(4)
        if (k > 2) REG_PASS(2)
        REG_PASS(1)
    }

    if (t < 128) {
        #pragma unroll
        for (int r4 = 0; r4 < 4; ++r4) {
            float4 o;
            o.x = (float)(4095u - (unsigned int)(key[r4 * 4 + 0] & 0xFFFFFFFFu));
            o.y = (float)(4095u - (unsigned int)(key[r4 * 4 + 1] & 0xFFFFFFFFu));
            o.z = (float)(4095u - (unsigned int)(key[r4 * 4 + 2] & 0xFFFFFFFFu));
            o.w = (float)(4095u - (unsigned int)(key[r4 * 4 + 3] & 0xFFFFFFFFu));
            *(float4*)&out_idx[(size_t)qrow * TOPK + (t << 4) + r4 * 4] = o;
        }
    }
}

extern "C" void kernel_launch(void* const* d_in, const int* in_sizes, int n_in,
                              void* d_out, int out_size, void* d_ws, size_t ws_size,
                              hipStream_t stream) {
    const float* q = (const float*)d_in[0];
    const float* k = (const float*)d_in[1];
    const float* w = (const float*)d_in[2];

    float* out        = (float*)d_out;
    float* out_topk   = out;
    float* out_scores = out + (size_t)SQ * TOPK;

    // Scratch plan: qs (32MB) + ks (2MB). Prefer d_ws; fall back to the
    // topk-index region for qs (written only by the final topk kernels).
    short8* qs;
    short8* ks;
    if (ws_size >= QS_BYTES + KS_BYTES) {
        qs = (short8*)d_ws;
        ks = (short8*)((char*)d_ws + QS_BYTES);
    } else if (ws_size >= KS_BYTES) {
        qs = (short8*)out_topk;
        ks = (short8*)d_ws;
    } else {
        qs = (short8*)out_topk;
        ks = nullptr;   // scores kernel falls back to in-kernel K conversion
    }

    split_q_kernel<<<SQ * NH * 16 / 256, 256, 0, stream>>>(q, qs);
    if (ks) split_k_kernel<<<SK * 16 / 256, 256, 0, stream>>>(k, ks);

    scores_kernel<<<dim3(64, 32), 256, 0, stream>>>(qs, ks, k, w, out_scores);

    topk_kernel<2048><<<2048, 128, 0, stream>>>(out_scores, out_topk, 0);
    topk_kernel<4096><<<2048, 256, 0, stream>>>(out_scores, out_topk, 2048);
}

// Round 10
// 302.726 us; speedup vs baseline: 1.3743x; 1.3709x over previous
//
#include <hip/hip_runtime.h>
#include <cmath>

#define SQ 4096
#define SK 4096
#define NH 16
#define DH 128
#define TQ 64
#define TK 64
#define TOPK 2048
#define NEG_SENTINEL (-3.0e38f)

typedef __attribute__((ext_vector_type(8))) short short8;
typedef __attribute__((ext_vector_type(4))) float f32x4;

#define QS_BYTES ((size_t)64 * 16 * 2 * 1024 * 16)   // [qtile][head][part][unit16B]

// Split f32 x into bf16 hi + bf16 lo (truncation split; residual exact).
__device__ __forceinline__ void cvt8(const float4 x0, const float4 x1,
                                     short8& hv, short8& lv) {
    const float xs[8] = {x0.x, x0.y, x0.z, x0.w, x1.x, x1.y, x1.z, x1.w};
    #pragma unroll
    for (int j = 0; j < 8; ++j) {
        const unsigned int b = __float_as_uint(xs[j]);
        const float hf = __uint_as_float(b & 0xFFFF0000u);
        const float r = xs[j] - hf;
        hv[j] = (short)(b >> 16);
        lv[j] = (short)(__float_as_uint(r) >> 16);
    }
}

__device__ __forceinline__ void gload_lds16(const void* g, void* l) {
    __builtin_amdgcn_global_load_lds(
        (const __attribute__((address_space(1))) unsigned int*)g,
        (__attribute__((address_space(3))) unsigned int*)l,
        16, 0, 0);
}

// ---------------------------------------------------------------------------
// Kernel 0: pre-split Q (validated round 6/7).
// ---------------------------------------------------------------------------
__global__ __launch_bounds__(256) void split_q_kernel(
    const float* __restrict__ qg,    // [SQ][NH][DH]
    short8* __restrict__ qs)         // [64][16][2][1024] 16B units
{
    const int gidx = blockIdx.x * 256 + threadIdx.x;   // [row][h][c]
    const int c   = gidx & 15;
    const int h   = (gidx >> 4) & 15;
    const int row = gidx >> 8;
    const size_t gb = ((size_t)row * NH + h) * DH + c * 8;
    const float4 x0 = *(const float4*)&qg[gb];
    const float4 x1 = *(const float4*)&qg[gb + 4];
    short8 hv, lv;
    cvt8(x0, x1, hv, lv);
    const int tile = row >> 6;
    const int r    = row & 63;
    const int u    = c * 64 + (r ^ (c & 7));
    const size_t base = (size_t)(tile * 16 + h) * 2048;
    qs[base + u]        = hv;
    qs[base + 1024 + u] = lv;
}

// ---------------------------------------------------------------------------
// Kernel 1: scores — EXACT round-6 structure (validated ~120us): Q staged per
// head via global_load_lds from the pre-split layout; K fragments in regs
// (cvt once per block); 3-term split MFMA; 36KB LDS -> 4 blocks/CU.
// ---------------------------------------------------------------------------
__global__ __launch_bounds__(256, 4) void scores_kernel(
    const short8* __restrict__ qs,   // pre-split Q
    const float* __restrict__ kg,    // [SK][DH]
    const float* __restrict__ wg,    // [SQ][NH]
    float* __restrict__ scores)      // [SQ][SK]
{
    const int bk = blockIdx.x;
    const int bq = blockIdx.y;
    const int qbase = bq * TQ;
    const int kbase = bk * TK;
    const int tid = threadIdx.x;

    if (bk > bq) {
        const float4 minf = make_float4(NEG_SENTINEL, NEG_SENTINEL, NEG_SENTINEL, NEG_SENTINEL);
        #pragma unroll
        for (int it = 0; it < 4; ++it) {
            int idx = it * 256 + tid;
            int r  = idx >> 4;
            int c4 = idx & 15;
            *(float4*)&scores[(size_t)(qbase + r) * SK + kbase + (c4 << 2)] = minf;
        }
        return;
    }

    __shared__ short8 QsH[1024], QsL[1024];   // 16KB + 16KB
    __shared__ float  Wl[TQ * NH];            // 4KB

    const int lane = tid & 63;
    const int wid  = tid >> 6;
    const int wr   = wid >> 1;
    const int wc   = wid & 1;
    const int l15  = lane & 15;
    const int l4   = lane >> 4;

    #pragma unroll
    for (int it = 0; it < 4; ++it) {
        const int i = tid + it * 256;
        Wl[i] = wg[(size_t)qbase * NH + i] * 0.08838834764831845f;
    }

    short8 bh[2][4], bl[2][4];
    #pragma unroll
    for (int ni = 0; ni < 2; ++ni)
        #pragma unroll
        for (int s = 0; s < 4; ++s) {
            const int key = kbase + wc * 32 + ni * 16 + l15;
            const int c   = s * 4 + l4;
            const float4 x0 = *(const float4*)&kg[(size_t)key * DH + c * 8];
            const float4 x1 = *(const float4*)&kg[(size_t)key * DH + c * 8 + 4];
            cvt8(x0, x1, bh[ni][s], bl[ni][s]);
        }

    f32x4 sacc[2][2];
    #pragma unroll
    for (int mi = 0; mi < 2; ++mi)
        #pragma unroll
        for (int ni = 0; ni < 2; ++ni) sacc[mi][ni] = (f32x4){0.f, 0.f, 0.f, 0.f};

    for (int h = 0; h < NH; ++h) {
        __syncthreads();
        {
            const short8* hb = qs + (size_t)(bq * 16 + h) * 2048;
            #pragma unroll
            for (int cc = 0; cc < 4; ++cc) {
                const int c = wid * 4 + cc;
                gload_lds16(hb + c * 64 + lane,        &QsH[c * 64]);
                gload_lds16(hb + 1024 + c * 64 + lane, &QsL[c * 64]);
            }
        }
        __syncthreads();

        f32x4 lac[2][2];
        #pragma unroll
        for (int mi = 0; mi < 2; ++mi)
            #pragma unroll
            for (int ni = 0; ni < 2; ++ni) lac[mi][ni] = (f32x4){0.f, 0.f, 0.f, 0.f};

        #pragma unroll
        for (int s = 0; s < 4; ++s) {
            short8 ah[2], al[2];
            #pragma unroll
            for (int mi = 0; mi < 2; ++mi) {
                const int row = wr * 32 + mi * 16 + l15;
                const int c   = s * 4 + l4;
                const int u   = c * 64 + (row ^ (c & 7));
                ah[mi] = QsH[u];
                al[mi] = QsL[u];
            }
            #pragma unroll
            for (int mi = 0; mi < 2; ++mi)
                #pragma unroll
                for (int ni = 0; ni < 2; ++ni) {
                    lac[mi][ni] = __builtin_amdgcn_mfma_f32_16x16x32_bf16(ah[mi], bh[ni][s], lac[mi][ni], 0, 0, 0);
                    lac[mi][ni] = __builtin_amdgcn_mfma_f32_16x16x32_bf16(ah[mi], bl[ni][s], lac[mi][ni], 0, 0, 0);
                    lac[mi][ni] = __builtin_amdgcn_mfma_f32_16x16x32_bf16(al[mi], bh[ni][s], lac[mi][ni], 0, 0, 0);
                }
        }

        float wv[2][4];
        #pragma unroll
        for (int mi = 0; mi < 2; ++mi)
            #pragma unroll
            for (int j = 0; j < 4; ++j) {
                const int row = wr * 32 + mi * 16 + l4 * 4 + j;
                wv[mi][j] = Wl[row * NH + h];
            }
        #pragma unroll
        for (int mi = 0; mi < 2; ++mi)
            #pragma unroll
            for (int ni = 0; ni < 2; ++ni)
                #pragma unroll
                for (int j = 0; j < 4; ++j)
                    sacc[mi][ni][j] = fmaf(wv[mi][j], fmaxf(lac[mi][ni][j], 0.f), sacc[mi][ni][j]);
    }

    #pragma unroll
    for (int mi = 0; mi < 2; ++mi)
        #pragma unroll
        for (int ni = 0; ni < 2; ++ni)
            #pragma unroll
            for (int j = 0; j < 4; ++j) {
                const int q  = qbase + wr * 32 + mi * 16 + l4 * 4 + j;
                const int kk = kbase + wc * 32 + ni * 16 + l15;
                scores[(size_t)q * SK + kk] = (kk <= q) ? sacc[mi][ni][j] : NEG_SENTINEL;
            }
}

// ---------------------------------------------------------------------------
// Kernel 2a: rows 0..2047 — sorted 2048-prefix bitonic (validated, unchanged).
// ---------------------------------------------------------------------------
#define REG_PASS(J)                                                        \
    {                                                                      \
        _Pragma("unroll")                                                  \
        for (int r = 0; r < 16; ++r) {                                     \
            if ((r & (J)) == 0) {                                          \
                const int i = (t << 4) | r;                                \
                const bool up = ((i & k) == 0);                            \
                const unsigned long long a = key[r], b = key[r | (J)];     \
                const unsigned long long mx = a > b ? a : b;               \
                const unsigned long long mn = a > b ? b : a;               \
                key[r]       = up ? mx : mn;                               \
                key[r | (J)] = up ? mn : mx;                               \
            }                                                              \
        }                                                                  \
    }

template<int N>
__global__ __launch_bounds__(N / 16) void topk_kernel(
    const float* __restrict__ scores,
    float* __restrict__ out_idx,
    int row_base)
{
    __shared__ unsigned long long lds[N];

    const int qrow = row_base + blockIdx.x;
    const int t = threadIdx.x;
    const int sw = t & 15;

    unsigned long long key[16];
    {
        const float* rowp = scores + (size_t)qrow * SK + (t << 4);
        #pragma unroll
        for (int r4 = 0; r4 < 4; ++r4) {
            const float4 v = *(const float4*)(rowp + r4 * 4);
            const float vs[4] = {v.x, v.y, v.z, v.w};
            #pragma unroll
            for (int rr = 0; rr < 4; ++rr) {
                const int r = r4 * 4 + rr;
                const int i = (t << 4) | r;
                const unsigned int b = __float_as_uint(vs[rr]);
                const unsigned int u = (b & 0x80000000u) ? ~b : (b | 0x80000000u);
                key[r] = ((unsigned long long)u << 32) | (unsigned int)(4095 - i);
            }
        }
    }

    for (int k = 2; k <= N; k <<= 1) {
        for (int j = k >> 1; j >= 1024; j >>= 1) {
            __syncthreads();
            #pragma unroll
            for (int r = 0; r < 16; ++r) lds[(t << 4) | (r ^ sw)] = key[r];
            __syncthreads();
            #pragma unroll
            for (int r = 0; r < 16; ++r) {
                const int i = (t << 4) | r;
                const unsigned long long bb = lds[(((t << 4) | (r ^ sw))) ^ j];
                const bool take_max = (((i & k) == 0) == ((i & j) == 0));
                const bool agtb = key[r] > bb;
                key[r] = (take_max == agtb) ? key[r] : bb;
            }
        }
        {
            const int j0 = (k >> 1) < 512 ? (k >> 1) : 512;
            for (int j = j0; j >= 16; j >>= 1) {
                #pragma unroll
                for (int r = 0; r < 16; ++r) {
                    const int i = (t << 4) | r;
                    const unsigned long long bb =
                        (unsigned long long)__shfl_xor((long long)key[r], j >> 4, 64);
                    const bool take_max = (((i & k) == 0) == ((i & j) == 0));
                    const bool agtb = key[r] > bb;
                    key[r] = (take_max == agtb) ? key[r] : bb;
                }
            }
        }
        if (k > 8) REG_PASS(8)
        if (k > 4) REG_PASS(4)
        if (k > 2) REG_PASS(2)
        REG_PASS(1)
    }

    if (t < 128) {
        #pragma unroll
        for (int r4 = 0; r4 < 4; ++r4) {
            float4 o;
            o.x = (float)(4095u - (unsigned int)(key[r4 * 4 + 0] & 0xFFFFFFFFu));
            o.y = (float)(4095u - (unsigned int)(key[r4 * 4 + 1] & 0xFFFFFFFFu));
            o.z = (float)(4095u - (unsigned int)(key[r4 * 4 + 2] & 0xFFFFFFFFu));
            o.w = (float)(4095u - (unsigned int)(key[r4 * 4 + 3] & 0xFFFFFFFFu));
            *(float4*)&out_idx[(size_t)qrow * TOPK + (t << 4) + r4 * 4] = o;
        }
    }
}

// ---------------------------------------------------------------------------
// Kernel 2b: rows 2048..4095 — exact radix-select of the 2048th-largest u,
// stable compaction (jax tie-break: value desc, index asc), then bitonic
// sort of only the 2048 selected keys (256 thr x 8/thr).
// All valid scores >= 0 > sentinel, and rows here have >= 2049 valid entries,
// so the top-2048 is sentinel-free; sentinels (i > qrow) skip the histogram.
// ---------------------------------------------------------------------------
#define REG8(J)                                                            \
    {                                                                      \
        _Pragma("unroll")                                                  \
        for (int r = 0; r < 8; ++r) {                                      \
            if ((r & (J)) == 0) {                                          \
                const int i = (t << 3) | r;                                \
                const bool up = ((i & k) == 0);                            \
                const unsigned long long a = key[r], b = key[r | (J)];     \
                const unsigned long long mx = a > b ? a : b;               \
                const unsigned long long mn = a > b ? b : a;               \
                key[r]       = up ? mx : mn;                               \
                key[r | (J)] = up ? mn : mx;                               \
            }                                                              \
        }                                                                  \
    }

__global__ __launch_bounds__(256) void topk_select_kernel(
    const float* __restrict__ scores,
    float* __restrict__ out_idx,
    int row_base)
{
    __shared__ unsigned long long cld[2048];   // 16KB: compaction + LDS exchange
    __shared__ unsigned int hist[256];
    __shared__ unsigned int bcast[2];
    __shared__ unsigned int wsum[4];

    const int qrow = row_base + blockIdx.x;
    const int t    = threadIdx.x;
    const int lane = t & 63;
    const int wid  = t >> 6;

    // ---- load + monotone transform ----
    unsigned int u[16];
    {
        const float* rowp = scores + (size_t)qrow * SK + (t << 4);
        #pragma unroll
        for (int r4 = 0; r4 < 4; ++r4) {
            const float4 v = *(const float4*)(rowp + r4 * 4);
            const float vs[4] = {v.x, v.y, v.z, v.w};
            #pragma unroll
            for (int rr = 0; rr < 4; ++rr) {
                const unsigned int b = __float_as_uint(vs[rr]);
                u[r4 * 4 + rr] = (b & 0x80000000u) ? ~b : (b | 0x80000000u);
            }
        }
    }

    // ---- radix select: Tu = 2048th largest u (valid entries only) ----
    unsigned int pfx = 0, count_gt = 0;
    for (int shift = 24; shift >= 0; shift -= 8) {
        const unsigned int maskhi = (shift == 24) ? 0u : (0xFFFFFFFFu << (shift + 8));
        hist[t] = 0;
        __syncthreads();
        #pragma unroll
        for (int r = 0; r < 16; ++r) {
            const int i = (t << 4) | r;
            if (i <= qrow && (u[r] & maskhi) == pfx)
                atomicAdd(&hist[(u[r] >> shift) & 255], 1u);
        }
        __syncthreads();
        const unsigned int my = hist[t];
        // inclusive suffix scan: hist[b] = sum_{b' >= b}
        for (int d = 1; d < 256; d <<= 1) {
            const unsigned int hv = hist[t] + ((t + d < 256) ? hist[t + d] : 0u);
            __syncthreads();
            hist[t] = hv;
            __syncthreads();
        }
        const unsigned int S = hist[t];
        if (count_gt + S >= 2048u && count_gt + S - my < 2048u) {
            bcast[0] = (unsigned int)t;
            bcast[1] = count_gt + S - my;
        }
        __syncthreads();
        pfx |= bcast[0] << shift;
        count_gt = bcast[1];
        __syncthreads();
    }
    const unsigned int Tu   = pfx;
    const unsigned int need = 2048u - count_gt;

    // ---- stable exclusive prefixes (ascending index) of (gt, eq) ----
    unsigned int gtb[16], eqb[16];
    unsigned int cgt = 0, ceq = 0;
    #pragma unroll
    for (int r = 0; r < 16; ++r) {
        gtb[r] = cgt; eqb[r] = ceq;
        cgt += (u[r] > Tu) ? 1u : 0u;
        ceq += (u[r] == Tu) ? 1u : 0u;
    }
    unsigned int pack = (cgt << 16) | ceq;
    unsigned int inc = pack;
    #pragma unroll
    for (int d = 1; d < 64; d <<= 1) {
        const unsigned int v = __shfl_up(inc, d, 64);
        if (lane >= d) inc += v;
    }
    const unsigned int ex = inc - pack;
    if (lane == 63) wsum[wid] = inc;
    __syncthreads();
    unsigned int wex = 0;
    #pragma unroll
    for (int ww = 0; ww < 4; ++ww) wex += (ww < wid) ? wsum[ww] : 0u;
    const unsigned int gt0 = (wex >> 16) + (ex >> 16);
    const unsigned int eq0 = (wex & 0xFFFFu) + (ex & 0xFFFFu);

    // ---- compact selected 2048 keys into cld ----
    #pragma unroll
    for (int r = 0; r < 16; ++r) {
        const unsigned int g = gt0 + gtb[r];
        const unsigned int e = eq0 + eqb[r];
        const int i = (t << 4) | r;
        const unsigned long long kk =
            ((unsigned long long)u[r] << 32) | (unsigned int)(4095 - i);
        if (u[r] > Tu) {
            cld[g + (e < need ? e : need)] = kk;
        } else if (u[r] == Tu && e < need) {
            cld[g + e] = kk;
        }
    }
    __syncthreads();

    // ---- bitonic sort 2048 keys, 256 threads x 8/thread (i = t*8 + r) ----
    unsigned long long key[8];
    #pragma unroll
    for (int r = 0; r < 8; ++r) key[r] = cld[(t << 3) | r];

    const int sw8 = t & 7;
    for (int k = 2; k <= 2048; k <<= 1) {
        // LDS passes j = 1024, 512 (cross-wave); swizzle phys = x ^ (t&7)
        for (int j = k >> 1; j >= 512; j >>= 1) {
            __syncthreads();
            #pragma unroll
            for (int r = 0; r < 8; ++r) cld[(t << 3) | (r ^ sw8)] = key[r];
            __syncthreads();
            #pragma unroll
            for (int r = 0; r < 8; ++r) {
                const int i = (t << 3) | r;
                const unsigned long long bb = cld[(((t << 3) | (r ^ sw8))) ^ j];
                const bool take_max = (((i & k) == 0) == ((i & j) == 0));
                const bool agtb = key[r] > bb;
                key[r] = (take_max == agtb) ? key[r] : bb;
            }
        }
        // shfl passes j = 256..8 (lane xor 32..1)
        {
            const int j0 = (k >> 1) < 256 ? (k >> 1) : 256;
            for (int j = j0; j >= 8; j >>= 1) {
                #pragma unroll
                for (int r = 0; r < 8; ++r) {
                    const int i = (t << 3) | r;
                    const unsigned long long bb =
                        (unsigned long long)__shfl_xor((long long)key[r], j >> 3, 64);
                    const bool take_max = (((i & k) == 0) == ((i & j) == 0));
                    const bool agtb = key[r] > bb;
                    key[r] = (take_max == agtb) ? key[r] : bb;
                }
            }
        }
        if (k > 4) REG8(4)
        if (k > 2) REG8(2)
        REG8(1)
    }

    // ---- emit 2048 indices ----
    #pragma unroll
    for (int r2 = 0; r2 < 2; ++r2) {
        float4 o;
        o.x = (float)(4095u - (unsigned int)(key[r2 * 4 + 0] & 0xFFFFFFFFu));
        o.y = (float)(4095u - (unsigned int)(key[r2 * 4 + 1] & 0xFFFFFFFFu));
        o.z = (float)(4095u - (unsigned int)(key[r2 * 4 + 2] & 0xFFFFFFFFu));
        o.w = (float)(4095u - (unsigned int)(key[r2 * 4 + 3] & 0xFFFFFFFFu));
        *(float4*)&out_idx[(size_t)qrow * TOPK + (t << 3) + r2 * 4] = o;
    }
}

extern "C" void kernel_launch(void* const* d_in, const int* in_sizes, int n_in,
                              void* d_out, int out_size, void* d_ws, size_t ws_size,
                              hipStream_t stream) {
    const float* q = (const float*)d_in[0];
    const float* k = (const float*)d_in[1];
    const float* w = (const float*)d_in[2];

    float* out        = (float*)d_out;
    float* out_topk   = out;
    float* out_scores = out + (size_t)SQ * TOPK;

    short8* qs = (ws_size >= QS_BYTES) ? (short8*)d_ws : (short8*)out_topk;

    split_q_kernel<<<SQ * NH * 16 / 256, 256, 0, stream>>>(q, qs);

    scores_kernel<<<dim3(SK / TK, SQ / TQ), 256, 0, stream>>>(qs, k, w, out_scores);

    topk_kernel<2048><<<2048, 128, 0, stream>>>(out_scores, out_topk, 0);
    topk_select_kernel<<<2048, 256, 0, stream>>>(out_scores, out_topk, 2048);
}